// Round 1
// baseline (56.369 us; speedup 1.0000x reference)
//
#include <hip/hip_runtime.h>

constexpr int C  = 640;
constexpr int HW = 25;
constexpr int CH = 160;          // channels per LDS chunk
constexpr int NCHUNK = C / CH;   // 4
constexpr int CH4 = CH * HW / 4; // 1000 float4 per matrix per chunk

__device__ __forceinline__ float rl(float x, int lane) {
  return __uint_as_float(__builtin_amdgcn_readlane(__float_as_uint(x), lane));
}

__global__ __launch_bounds__(256, 3) void emd_kernel(
    const float* __restrict__ support, const float* __restrict__ query,
    float* __restrict__ out)
{
  const int n   = blockIdx.x;
  const int tid = threadIdx.x;

  __shared__ union alignas(16) {
    struct { float Qs[CH * HW]; float Ss[CH * HW]; } st; // 32000 B
    float Gp[10 * 625];                                   // 25000 B (aliased)
  } sa;
  __shared__ float G[625];
  __shared__ float simm[625];
  __shared__ float sQ[25], sS[25], ssQ[25], ssS[25];
  __shared__ float am[25], bm[25], nq[25], ns[25];
  __shared__ float scal[2];

  const float4* Qg = reinterpret_cast<const float4*>(query   + (size_t)n * C * HW);
  const float4* Sg = reinterpret_cast<const float4*>(support + (size_t)n * C * HW);

  // ---- Phase 1: Gram + column moments ----
  float acc[5][5];
  #pragma unroll
  for (int i = 0; i < 5; ++i)
    #pragma unroll
    for (int j = 0; j < 5; ++j) acc[i][j] = 0.f;

  const int tile = tid % 25;          // 5x5 tile id
  const int grp  = tid / 25;          // channel group 0..9 (tid<250)
  const int u0 = (tile / 5) * 5, v0 = (tile % 5) * 5;
  float csum = 0.f, csum2 = 0.f;      // column moments (tid<50)
  const int col = (tid < 25) ? tid : tid - 25;

  for (int ch = 0; ch < NCHUNK; ++ch) {
    __syncthreads();   // previous chunk consumers done
    for (int idx = tid; idx < CH4; idx += 256)
      reinterpret_cast<float4*>(sa.st.Qs)[idx] = Qg[ch * CH4 + idx];
    for (int idx = tid; idx < CH4; idx += 256)
      reinterpret_cast<float4*>(sa.st.Ss)[idx] = Sg[ch * CH4 + idx];
    __syncthreads();

    if (tid < 250) {
      const float* qb = sa.st.Qs + grp * 16 * HW + u0;
      const float* sb = sa.st.Ss + grp * 16 * HW + v0;
      #pragma unroll 4
      for (int cc = 0; cc < 16; ++cc) {
        float q[5], s[5];
        #pragma unroll
        for (int i = 0; i < 5; ++i) q[i] = qb[cc * HW + i];
        #pragma unroll
        for (int j = 0; j < 5; ++j) s[j] = sb[cc * HW + j];
        #pragma unroll
        for (int i = 0; i < 5; ++i)
          #pragma unroll
          for (int j = 0; j < 5; ++j)
            acc[i][j] = fmaf(q[i], s[j], acc[i][j]);
      }
    }
    if (tid < 50) {
      const float* base = (tid < 25) ? sa.st.Qs : sa.st.Ss;
      for (int c = 0; c < CH; ++c) {
        float x = base[c * HW + col];
        csum += x;
        csum2 = fmaf(x, x, csum2);
      }
    }
  }
  __syncthreads();   // all reads of Qs/Ss done; safe to alias with Gp

  if (tid < 250) {
    #pragma unroll
    for (int i = 0; i < 5; ++i)
      #pragma unroll
      for (int j = 0; j < 5; ++j)
        sa.Gp[grp * 625 + (u0 + i) * 25 + (v0 + j)] = acc[i][j];
  }
  if (tid < 25)      { sQ[col] = csum; ssQ[col] = csum2; }
  else if (tid < 50) { sS[col] = csum; ssS[col] = csum2; }
  __syncthreads();

  for (int p = tid; p < 625; p += 256) {
    float g = 0.f;
    #pragma unroll
    for (int gg = 0; gg < 10; ++gg) g += sa.Gp[gg * 625 + p];
    G[p] = g;
  }
  __syncthreads();

  // marginals (pre-centering!) and norms (centered via moments)
  if (tid < 25) {
    float s = 0.f;
    #pragma unroll
    for (int j = 0; j < 25; ++j) s += G[tid * 25 + j];
    am[tid] = fmaxf(s * (1.f / 25.f), 0.f) + 0.001f + 1e-5f;
    float var = ssQ[tid] - sQ[tid] * sQ[tid] * (1.f / C);
    nq[tid] = fmaxf(sqrtf(fmaxf(var, 0.f)), 1e-8f);
  } else if (tid >= 32 && tid < 57) {
    int v = tid - 32;
    float s = 0.f;
    #pragma unroll
    for (int u = 0; u < 25; ++u) s += G[u * 25 + v];
    bm[v] = fmaxf(s * (1.f / 25.f), 0.f) + 0.001f + 1e-5f;
    float var = ssS[v] - sS[v] * sS[v] * (1.f / C);
    ns[v] = fmaxf(sqrtf(fmaxf(var, 0.f)), 1e-8f);
  }
  __syncthreads();
  if (tid == 0)  { float s = 0.f; for (int i = 0; i < 25; ++i) s += am[i]; scal[0] = 25.f / s; }
  if (tid == 64) { float s = 0.f; for (int i = 0; i < 25; ++i) s += bm[i]; scal[1] = 25.f / s; }
  __syncthreads();
  if (tid < 25)                    am[tid]      *= scal[0];
  else if (tid >= 32 && tid < 57)  bm[tid - 32] *= scal[1];

  // sim map
  for (int p = tid; p < 625; p += 256) {
    int u = p / 25, v = p % 25;
    float cov = G[p] - sQ[u] * sS[v] * (1.f / C);
    simm[p] = cov / (nq[u] * ns[v]);
  }
  __syncthreads();

  if (tid >= 64) return;   // Sinkhorn on wave 0 only (no barriers below)

  // ---- Phase 2: Sinkhorn, lane u holds row u and col u of K ----
  const int lane = tid;
  const int u = (lane < 25) ? lane : 24;
  const float a_u = am[u], b_u = bm[u];
  float Krow[25], Kcol[25];
  #pragma unroll
  for (int j = 0; j < 25; ++j) {
    Krow[j] = expf(-20.f * (1.f - simm[u * 25 + j]));
    Kcol[j] = expf(-20.f * (1.f - simm[j * 25 + u]));
  }

  float vv = 1.0f, uu = 0.0f;
  #pragma unroll 1
  for (int it = 0; it < 100; ++it) {
    float s0 = 0, s1 = 0, s2 = 0, s3 = 0, s4 = 0;
    #pragma unroll
    for (int j = 0; j < 25; j += 5) {
      s0 = fmaf(Krow[j + 0], rl(vv, j + 0), s0);
      s1 = fmaf(Krow[j + 1], rl(vv, j + 1), s1);
      s2 = fmaf(Krow[j + 2], rl(vv, j + 2), s2);
      s3 = fmaf(Krow[j + 3], rl(vv, j + 3), s3);
      s4 = fmaf(Krow[j + 4], rl(vv, j + 4), s4);
    }
    uu = a_u / ((((s0 + s1) + (s2 + s3)) + s4) + 1e-30f);

    s0 = s1 = s2 = s3 = s4 = 0;
    #pragma unroll
    for (int j = 0; j < 25; j += 5) {
      s0 = fmaf(Kcol[j + 0], rl(uu, j + 0), s0);
      s1 = fmaf(Kcol[j + 1], rl(uu, j + 1), s1);
      s2 = fmaf(Kcol[j + 2], rl(uu, j + 2), s2);
      s3 = fmaf(Kcol[j + 3], rl(uu, j + 3), s3);
      s4 = fmaf(Kcol[j + 4], rl(uu, j + 4), s4);
    }
    vv = b_u / ((((s0 + s1) + (s2 + s3)) + s4) + 1e-30f);
  }
  {  // final u = a / (K v + 1e-30)
    float s0 = 0, s1 = 0, s2 = 0, s3 = 0, s4 = 0;
    #pragma unroll
    for (int j = 0; j < 25; j += 5) {
      s0 = fmaf(Krow[j + 0], rl(vv, j + 0), s0);
      s1 = fmaf(Krow[j + 1], rl(vv, j + 1), s1);
      s2 = fmaf(Krow[j + 2], rl(vv, j + 2), s2);
      s3 = fmaf(Krow[j + 3], rl(vv, j + 3), s3);
      s4 = fmaf(Krow[j + 4], rl(vv, j + 4), s4);
    }
    uu = a_u / ((((s0 + s1) + (s2 + s3)) + s4) + 1e-30f);
  }

  float part = 0.f;
  if (lane < 25) {
    float t0 = 0.f;
    #pragma unroll
    for (int j = 0; j < 25; ++j)
      t0 = fmaf(simm[u * 25 + j] * Krow[j], rl(vv, j), t0);
    part = uu * t0;
  }
  #pragma unroll
  for (int off = 32; off; off >>= 1) part += __shfl_xor(part, off);
  if (lane == 0) out[n] = part * 0.5f;   // * TEMPERATURE / hw = 12.5/25
}

extern "C" void kernel_launch(void* const* d_in, const int* in_sizes, int n_in,
                              void* d_out, int out_size, void* d_ws, size_t ws_size,
                              hipStream_t stream) {
  const float* support = (const float*)d_in[0];
  const float* query   = (const float*)d_in[1];
  float* out = (float*)d_out;
  const int N = in_sizes[0] / (C * HW);   // 600
  emd_kernel<<<dim3(N), dim3(256), 0, stream>>>(support, query, out);
}

// Round 2
// 39.453 us; speedup vs baseline: 1.4288x; 1.4288x over previous
//
#include <hip/hip_runtime.h>

constexpr int C  = 640;
constexpr int HW = 25;
constexpr int CH = 160;          // channels per LDS chunk
constexpr int NCHUNK = C / CH;   // 4
constexpr int CH4 = CH * HW / 4; // 1000 float4 per matrix per chunk
constexpr int WSTRIDE = 704;     // floats per sample in ws: [0,625) sim, [625,650) a, [650,675) b

__device__ __forceinline__ float rl(float x, int lane) {
  return __uint_as_float(__builtin_amdgcn_readlane(__float_as_uint(x), lane));
}

// ---------------- Kernel 1: Gram -> sim, marginals ----------------
__global__ __launch_bounds__(256, 3) void emd_sim(
    const float* __restrict__ support, const float* __restrict__ query,
    float* __restrict__ ws)
{
  const int n   = blockIdx.x;
  const int tid = threadIdx.x;

  __shared__ union alignas(16) {
    struct { float Qs[CH * HW]; float Ss[CH * HW]; } st; // 32000 B
    float Gp[10 * 625];                                   // 25000 B (aliased)
  } sa;
  __shared__ float G[625];
  __shared__ float sQ[25], sS[25], ssQ[25], ssS[25];
  __shared__ float am[25], bm[25], nq[25], ns[25];
  __shared__ float scal[2];

  const float4* Qg = reinterpret_cast<const float4*>(query   + (size_t)n * C * HW);
  const float4* Sg = reinterpret_cast<const float4*>(support + (size_t)n * C * HW);
  float* w = ws + (size_t)n * WSTRIDE;

  float acc[5][5];
  #pragma unroll
  for (int i = 0; i < 5; ++i)
    #pragma unroll
    for (int j = 0; j < 5; ++j) acc[i][j] = 0.f;

  const int tile = tid % 25;
  const int grp  = tid / 25;
  const int u0 = (tile / 5) * 5, v0 = (tile % 5) * 5;
  float csum = 0.f, csum2 = 0.f;
  const int col = (tid < 25) ? tid : tid - 25;

  for (int ch = 0; ch < NCHUNK; ++ch) {
    __syncthreads();
    for (int idx = tid; idx < CH4; idx += 256)
      reinterpret_cast<float4*>(sa.st.Qs)[idx] = Qg[ch * CH4 + idx];
    for (int idx = tid; idx < CH4; idx += 256)
      reinterpret_cast<float4*>(sa.st.Ss)[idx] = Sg[ch * CH4 + idx];
    __syncthreads();

    if (tid < 250) {
      const float* qb = sa.st.Qs + grp * 16 * HW + u0;
      const float* sb = sa.st.Ss + grp * 16 * HW + v0;
      #pragma unroll 4
      for (int cc = 0; cc < 16; ++cc) {
        float q[5], s[5];
        #pragma unroll
        for (int i = 0; i < 5; ++i) q[i] = qb[cc * HW + i];
        #pragma unroll
        for (int j = 0; j < 5; ++j) s[j] = sb[cc * HW + j];
        #pragma unroll
        for (int i = 0; i < 5; ++i)
          #pragma unroll
          for (int j = 0; j < 5; ++j)
            acc[i][j] = fmaf(q[i], s[j], acc[i][j]);
      }
    }
    if (tid < 50) {
      const float* base = (tid < 25) ? sa.st.Qs : sa.st.Ss;
      for (int c = 0; c < CH; ++c) {
        float x = base[c * HW + col];
        csum += x;
        csum2 = fmaf(x, x, csum2);
      }
    }
  }
  __syncthreads();   // reads of Qs/Ss done; safe to alias with Gp

  if (tid < 250) {
    #pragma unroll
    for (int i = 0; i < 5; ++i)
      #pragma unroll
      for (int j = 0; j < 5; ++j)
        sa.Gp[grp * 625 + (u0 + i) * 25 + (v0 + j)] = acc[i][j];
  }
  if (tid < 25)      { sQ[col] = csum; ssQ[col] = csum2; }
  else if (tid < 50) { sS[col] = csum; ssS[col] = csum2; }
  __syncthreads();

  for (int p = tid; p < 625; p += 256) {
    float g = 0.f;
    #pragma unroll
    for (int gg = 0; gg < 10; ++gg) g += sa.Gp[gg * 625 + p];
    G[p] = g;
  }
  __syncthreads();

  if (tid < 25) {
    float s = 0.f;
    #pragma unroll
    for (int j = 0; j < 25; ++j) s += G[tid * 25 + j];
    am[tid] = fmaxf(s * (1.f / 25.f), 0.f) + 0.001f + 1e-5f;
    float var = ssQ[tid] - sQ[tid] * sQ[tid] * (1.f / C);
    nq[tid] = fmaxf(sqrtf(fmaxf(var, 0.f)), 1e-8f);
  } else if (tid >= 32 && tid < 57) {
    int v = tid - 32;
    float s = 0.f;
    #pragma unroll
    for (int u = 0; u < 25; ++u) s += G[u * 25 + v];
    bm[v] = fmaxf(s * (1.f / 25.f), 0.f) + 0.001f + 1e-5f;
    float var = ssS[v] - sS[v] * sS[v] * (1.f / C);
    ns[v] = fmaxf(sqrtf(fmaxf(var, 0.f)), 1e-8f);
  }
  __syncthreads();
  if (tid == 0)  { float s = 0.f; for (int i = 0; i < 25; ++i) s += am[i]; scal[0] = 25.f / s; }
  if (tid == 64) { float s = 0.f; for (int i = 0; i < 25; ++i) s += bm[i]; scal[1] = 25.f / s; }
  __syncthreads();

  if (tid < 25)                    w[625 + tid]      = am[tid] * scal[0];
  else if (tid >= 32 && tid < 57)  w[650 + tid - 32] = bm[tid - 32] * scal[1];

  for (int p = tid; p < 625; p += 256) {
    int u = p / 25, v = p % 25;
    float cov = G[p] - sQ[u] * sS[v] * (1.f / C);
    w[p] = cov / (nq[u] * ns[v]);
  }
}

// ---------------- Kernel 2: Sinkhorn + reduction, one wave/sample ----------------
__global__ __launch_bounds__(64) void emd_sink(
    const float* __restrict__ ws, float* __restrict__ out)
{
  const int n    = blockIdx.x;
  const int lane = threadIdx.x;
  const int u    = (lane < 25) ? lane : 24;
  const float* w = ws + (size_t)n * WSTRIDE;

  float simr[25], Krow[25], Kcol[25];
  #pragma unroll
  for (int j = 0; j < 25; ++j) simr[j] = w[u * 25 + j];
  #pragma unroll
  for (int j = 0; j < 25; ++j) Kcol[j] = __expf(-20.f * (1.f - w[j * 25 + u]));
  #pragma unroll
  for (int j = 0; j < 25; ++j) Krow[j] = __expf(-20.f * (1.f - simr[j]));
  const float a_u = w[625 + u], b_u = w[650 + u];

  float vv = 1.0f, uu = 0.0f, vold = 1.0f;
  #pragma unroll 1
  for (int it = 0; it < 100; ++it) {
    float s0 = 0, s1 = 0, s2 = 0, s3 = 0, s4 = 0;
    #pragma unroll
    for (int j = 0; j < 25; j += 5) {
      s0 = fmaf(Krow[j + 0], rl(vv, j + 0), s0);
      s1 = fmaf(Krow[j + 1], rl(vv, j + 1), s1);
      s2 = fmaf(Krow[j + 2], rl(vv, j + 2), s2);
      s3 = fmaf(Krow[j + 3], rl(vv, j + 3), s3);
      s4 = fmaf(Krow[j + 4], rl(vv, j + 4), s4);
    }
    uu = a_u * __builtin_amdgcn_rcpf(((((s0 + s1) + (s2 + s3)) + s4) + 1e-30f));

    s0 = s1 = s2 = s3 = s4 = 0;
    #pragma unroll
    for (int j = 0; j < 25; j += 5) {
      s0 = fmaf(Kcol[j + 0], rl(uu, j + 0), s0);
      s1 = fmaf(Kcol[j + 1], rl(uu, j + 1), s1);
      s2 = fmaf(Kcol[j + 2], rl(uu, j + 2), s2);
      s3 = fmaf(Kcol[j + 3], rl(uu, j + 3), s3);
      s4 = fmaf(Kcol[j + 4], rl(uu, j + 4), s4);
    }
    vv = b_u * __builtin_amdgcn_rcpf(((((s0 + s1) + (s2 + s3)) + s4) + 1e-30f));

    if ((it & 7) == 7) {        // converged? (deterministic early exit)
      bool conv = fabsf(vv - vold) <= 1e-5f * fabsf(vv);
      if (__all(conv)) break;
      vold = vv;
    }
  }
  {  // final u = a / (K v + eps)
    float s0 = 0, s1 = 0, s2 = 0, s3 = 0, s4 = 0;
    #pragma unroll
    for (int j = 0; j < 25; j += 5) {
      s0 = fmaf(Krow[j + 0], rl(vv, j + 0), s0);
      s1 = fmaf(Krow[j + 1], rl(vv, j + 1), s1);
      s2 = fmaf(Krow[j + 2], rl(vv, j + 2), s2);
      s3 = fmaf(Krow[j + 3], rl(vv, j + 3), s3);
      s4 = fmaf(Krow[j + 4], rl(vv, j + 4), s4);
    }
    uu = a_u * __builtin_amdgcn_rcpf(((((s0 + s1) + (s2 + s3)) + s4) + 1e-30f));
  }

  float part = 0.f;
  if (lane < 25) {
    float t0 = 0.f;
    #pragma unroll
    for (int j = 0; j < 25; ++j)
      t0 = fmaf(simr[j] * Krow[j], rl(vv, j), t0);
    part = uu * t0;
  }
  #pragma unroll
  for (int off = 32; off; off >>= 1) part += __shfl_xor(part, off);
  if (lane == 0) out[n] = part * 0.5f;   // TEMPERATURE/hw = 12.5/25
}

extern "C" void kernel_launch(void* const* d_in, const int* in_sizes, int n_in,
                              void* d_out, int out_size, void* d_ws, size_t ws_size,
                              hipStream_t stream) {
  const float* support = (const float*)d_in[0];
  const float* query   = (const float*)d_in[1];
  float* out = (float*)d_out;
  float* ws  = (float*)d_ws;
  const int N = in_sizes[0] / (C * HW);   // 600
  emd_sim <<<dim3(N), dim3(256), 0, stream>>>(support, query, ws);
  emd_sink<<<dim3(N), dim3(64),  0, stream>>>(ws, out);
}